// Round 15
// baseline (89.280 us; speedup 1.0000x reference)
//
#include <hip/hip_runtime.h>
#include <hip/hip_bf16.h>

#define NB 20000      // batch
#define KN 16         // neighbors
#define D 256
#define KDIM 512      // 2*D
#define MDIM 512      // 2*OUT stacked
#define NTOT 100000   // feature table rows

// prep kernel block-role ranges
#define PB_W    256                    // convW blocks
#define PB_CONV 1600                   // fp8-table conversion blocks
#define PB_SELF 1250                   // self-gather blocks (16 rows each)
#define PB_TOT  (PB_W + PB_CONV + PB_SELF)

typedef __bf16 bf16x8 __attribute__((ext_vector_type(8)));
typedef float f32x4 __attribute__((ext_vector_type(4)));

__device__ inline unsigned short f2bf(float f) {
    union { float f; unsigned int u; } a; a.f = f;
    unsigned int u = a.u;
    unsigned int r = (u + 0x7FFFu + ((u >> 16) & 1u)) >> 16;   // RNE
    return (unsigned short)r;
}

// ---- OCP e4m3fn encode (software fallback, RNE) ----
__device__ inline unsigned int f2fp8(float v) {
    unsigned int s = (__float_as_uint(v) >> 31) << 7;
    float av = fabsf(v);
    if (av >= 448.f) return s | 0x7Eu;
    if (av < 0.015625f) {
        unsigned int m = (unsigned int)rintf(av * 512.f);
        return s | m;
    }
    int ex; float fr = frexpf(av, &ex);
    int m = (int)rintf(fr * 16.f - 8.f);
    int e = ex - 1;
    if (m == 8) { m = 0; e += 1; }
    if (e > 8) return s | 0x7Eu;
    return s | (unsigned int)((e + 7) << 3) | (unsigned int)m;
}

#if __has_builtin(__builtin_amdgcn_cvt_f32_fp8)
#define FP8_DEC(d, i) __builtin_amdgcn_cvt_f32_fp8((d), (i))
#else
__device__ inline float fp8_sw_dec(unsigned int d, int i) {
    unsigned int b = (d >> (i * 8)) & 0xFFu;
    unsigned int s = b >> 7, ef = (b >> 3) & 15u, m = b & 7u;
    float v = (ef == 0) ? (float)m * 0.001953125f
                        : __uint_as_float(((ef + 120u) << 23) | (m << 20));
    return s ? -v : v;
}
#define FP8_DEC(d, i) fp8_sw_dec((d), (i))
#endif

// --- prep kernel: 3 block-role ranges (R13-proven) ---
__global__ __launch_bounds__(256) void prep_kernel(
        const float* __restrict__ W1, const float* __restrict__ W2,
        const float* __restrict__ feat, const int* __restrict__ nodes,
        unsigned short* __restrict__ Wc, unsigned int* __restrict__ tab,
        unsigned short* __restrict__ comb) {
    int blk = blockIdx.x;
    int tid = threadIdx.x;

    if (blk < PB_W) {
        int i = blk * 256 + tid;                     // 65536 float4 chunks
        float4 v = (i < 32768) ? reinterpret_cast<const float4*>(W1)[i]
                               : reinterpret_cast<const float4*>(W2)[i - 32768];
        ushort4 o;
        o.x = f2bf(v.x); o.y = f2bf(v.y); o.z = f2bf(v.z); o.w = f2bf(v.w);
        reinterpret_cast<ushort4*>(Wc)[i] = o;
    } else if (blk < PB_W + PB_CONV) {
        const long long total = (long long)NTOT * D / 4;   // 6.4M dwords
        long long i = (long long)(blk - PB_W) * 256 + tid;
        const long long stride = (long long)PB_CONV * 256;
        for (; i < total; i += stride) {
            float4 v = reinterpret_cast<const float4*>(feat)[i];
#if __has_builtin(__builtin_amdgcn_cvt_pk_fp8_f32)
            int u = __builtin_amdgcn_cvt_pk_fp8_f32(v.x, v.y, 0, 0);
            u = __builtin_amdgcn_cvt_pk_fp8_f32(v.z, v.w, u, 1);
            tab[i] = (unsigned int)u;
#else
            tab[i] = f2fp8(v.x) | (f2fp8(v.y) << 8)
                   | (f2fp8(v.z) << 16) | (f2fp8(v.w) << 24);
#endif
        }
    } else {
        int base = (blk - PB_W - PB_CONV) * 16;
        int lane = tid & 63;
        int wid = tid >> 6;
        const float4* f4 = reinterpret_cast<const float4*>(feat);
        #pragma unroll
        for (int r = 0; r < 4; ++r) {
            int b = base + wid * 4 + r;
            int node = nodes[b];
            float4 s = f4[(size_t)node * 64 + lane];
            ushort4 sv; sv.x = f2bf(s.x); sv.y = f2bf(s.y);
            sv.z = f2bf(s.z); sv.w = f2bf(s.w);
            *reinterpret_cast<ushort4*>(comb + (size_t)b * KDIM + lane * 4) = sv;
        }
    }
}

// --- agg_n: neighbor-only gather from fp8 table -> mean half of comb ---
__global__ __launch_bounds__(256) void agg_n_kernel(
        const int* __restrict__ neigh, const unsigned int* __restrict__ tab,
        unsigned short* __restrict__ comb) {
    int w = threadIdx.x >> 6;
    int lane = threadIdx.x & 63;
    int b = blockIdx.x * 4 + w;                      // grid = 5000
    int nb = b * KN;

    float m0 = 0.f, m1 = 0.f, m2 = 0.f, m3 = 0.f;
    #pragma unroll
    for (int k = 0; k < KN; ++k) {
        int idx = neigh[nb + k];
        unsigned int d = tab[(size_t)idx * 64 + lane];   // 4B/lane = 4 fp8
        m0 += FP8_DEC(d, 0); m1 += FP8_DEC(d, 1);
        m2 += FP8_DEC(d, 2); m3 += FP8_DEC(d, 3);
    }
    const float inv = 1.0f / 16.0f;
    ushort4 mv; mv.x = f2bf(m0 * inv); mv.y = f2bf(m1 * inv);
    mv.z = f2bf(m2 * inv); mv.w = f2bf(m3 * inv);
    *reinterpret_cast<ushort4*>(comb + (size_t)b * KDIM + D + lane * 4) = mv;
}

// --- gemm6: BM=256 x BN=80, BK=64, LDK=72; XCD pair-swizzle; reg-double-
//     buffered staging (T14): tile t+1 global loads issued BEFORE MFMA(t),
//     LDS write after the post-MFMA barrier -> memory stays busy under MFMA. ---
#define G4M 256
#define G4N 80
#define GBK2 64
#define LDK2 72
#define G4BLK 500     // (NB/G4N) * (MDIM/G4M)

__global__ __launch_bounds__(256) void gemm6_kernel(
        const unsigned short* __restrict__ Wc,    // [512][512] bf16
        const unsigned short* __restrict__ Cb,    // [20000][512] bf16
        float* __restrict__ out) {                // [512][20000] f32
    __shared__ __align__(16) unsigned short As[G4M * LDK2];   // 36.9KB
    __shared__ __align__(16) unsigned short Bs[G4N * LDK2];   // 11.5KB

    int b = blockIdx.x;
    const int q = G4BLK / 8, r = G4BLK % 8;       // 62, 4
    int xcd = b & 7, slot = b >> 3;
    int logical = (xcd < r) ? xcd * (q + 1) + slot
                            : r * (q + 1) + (xcd - r) * q + slot;
    int ntile = logical >> 1;                     // 0..249
    int mtile = logical & 1;                      // 0..1

    int tid = threadIdx.x;
    int lane = tid & 63;
    int wid = tid >> 6;                 // 0..3 -> m-slice of 64
    int mBase = mtile * G4M;
    int nBase = ntile * G4N;            // exact fit: 250*80 = 20000

    f32x4 acc[4][5] = {};

    int srow8 = tid >> 3;               // 0..31
    int scol8 = (tid & 7) * 8;          // elem col 0..56
    int rl = lane & 15;
    int kq = (lane >> 4) * 8;

    // staging registers (tile double-buffer lives in VGPRs)
    uint4 av[8];                        // A: 8 chunks/thread
    uint4 bv0, bv1, bv2;                // B: 2 chunks + 1 for tid<128

    int c1r = (tid + 256) >> 3, c1c = ((tid + 256) & 7) * 8;
    int c2r = (tid + 512) >> 3, c2c = ((tid + 512) & 7) * 8;

    auto load_tile = [&](int k0) {
        #pragma unroll
        for (int h = 0; h < 8; ++h) {
            int rr = srow8 + h * 32;
            av[h] = *reinterpret_cast<const uint4*>(
                Wc + (size_t)(mBase + rr) * KDIM + k0 + scol8);
        }
        bv0 = *reinterpret_cast<const uint4*>(
            Cb + (size_t)(nBase + (tid >> 3)) * KDIM + k0 + (tid & 7) * 8);
        bv1 = *reinterpret_cast<const uint4*>(
            Cb + (size_t)(nBase + c1r) * KDIM + k0 + c1c);
        if (tid < 128)
            bv2 = *reinterpret_cast<const uint4*>(
                Cb + (size_t)(nBase + c2r) * KDIM + k0 + c2c);
    };
    auto write_tile = [&]() {
        #pragma unroll
        for (int h = 0; h < 8; ++h) {
            int rr = srow8 + h * 32;
            *reinterpret_cast<uint4*>(&As[rr * LDK2 + scol8]) = av[h];
        }
        *reinterpret_cast<uint4*>(&Bs[(tid >> 3) * LDK2 + (tid & 7) * 8]) = bv0;
        *reinterpret_cast<uint4*>(&Bs[c1r * LDK2 + c1c]) = bv1;
        if (tid < 128)
            *reinterpret_cast<uint4*>(&Bs[c2r * LDK2 + c2c]) = bv2;
    };

    // prologue: tile 0 -> LDS
    load_tile(0);
    write_tile();
    __syncthreads();

    for (int kt = 0; kt < KDIM / GBK2; ++kt) {
        // issue next tile's global loads EARLY (in flight under MFMA)
        if (kt < KDIM / GBK2 - 1) load_tile((kt + 1) * GBK2);

        #pragma unroll
        for (int kk = 0; kk < GBK2; kk += 32) {
            bf16x8 af[4], bfr[5];
            #pragma unroll
            for (int i = 0; i < 4; ++i)
                af[i] = *reinterpret_cast<const bf16x8*>(
                    &As[(wid * 64 + i * 16 + rl) * LDK2 + kk + kq]);
            #pragma unroll
            for (int j = 0; j < 5; ++j)
                bfr[j] = *reinterpret_cast<const bf16x8*>(
                    &Bs[(j * 16 + rl) * LDK2 + kk + kq]);
            #pragma unroll
            for (int i = 0; i < 4; ++i)
                #pragma unroll
                for (int j = 0; j < 5; ++j)
                    acc[i][j] = __builtin_amdgcn_mfma_f32_16x16x32_bf16(
                        af[i], bfr[j], acc[i][j], 0, 0, 0);
        }
        __syncthreads();                 // all ds_reads of tile kt retired
        if (kt < KDIM / GBK2 - 1) {
            write_tile();                // regs (waited here, not earlier) -> LDS
            __syncthreads();             // tile kt+1 visible
        }
    }

    // epilogue: C/D layout col=lane&15, row=(lane>>4)*4+reg (verified);
    // non-temporal stores keep comb/Wc resident in L2
    int col = lane & 15;
    int rq = (lane >> 4) * 4;
    #pragma unroll
    for (int i = 0; i < 4; ++i) {
        int mRow = mBase + wid * 64 + i * 16 + rq;
        #pragma unroll
        for (int j = 0; j < 5; ++j) {
            int n = nBase + j * 16 + col;             // always < NB
            #pragma unroll
            for (int rr = 0; rr < 4; ++rr) {
                float x = acc[i][j][rr];
                x = x > 0.f ? x : 0.f;
                __builtin_nontemporal_store(x, &out[(size_t)(mRow + rr) * NB + n]);
            }
        }
    }
}

extern "C" void kernel_launch(void* const* d_in, const int* in_sizes, int n_in,
                              void* d_out, int out_size, void* d_ws, size_t ws_size,
                              hipStream_t stream) {
    const int*   nodes = (const int*)d_in[0];
    const int*   neigh = (const int*)d_in[1];
    const float* feat  = (const float*)d_in[2];
    const float* W1    = (const float*)d_in[3];
    const float* W2    = (const float*)d_in[4];
    float* out = (float*)d_out;

    // ws layout: Wc (512KB) | fp8 table (25.6MB) | comb (20.48MB)
    const size_t WC_BYTES  = (size_t)MDIM * KDIM * 2;
    const size_t TAB_BYTES = (size_t)NTOT * D;
    unsigned short* Wc   = (unsigned short*)d_ws;
    unsigned int*   tab  = (unsigned int*)((char*)d_ws + WC_BYTES);
    unsigned short* comb = (unsigned short*)((char*)d_ws + WC_BYTES + TAB_BYTES);

    prep_kernel<<<PB_TOT, 256, 0, stream>>>(W1, W2, feat, nodes, Wc, tab, comb);
    agg_n_kernel<<<NB / 4, 256, 0, stream>>>(neigh, tab, comb);
    gemm6_kernel<<<G4BLK, 256, 0, stream>>>(Wc, comb, out);
}

// Round 16
// 66.271 us; speedup vs baseline: 1.3472x; 1.3472x over previous
//
#include <hip/hip_runtime.h>
#include <hip/hip_bf16.h>

#define NB 20000      // batch
#define KN 16         // neighbors
#define D 256
#define KDIM 512      // 2*D
#define MDIM 512      // 2*OUT stacked
#define NTOT 100000   // feature table rows

// prep kernel block-role ranges
#define PB_W    256                    // convW blocks
#define PB_CONV 1600                   // fp8-table conversion blocks
#define PB_SELF 1250                   // self-gather blocks (16 rows each)
#define PB_TOT  (PB_W + PB_CONV + PB_SELF)

typedef __bf16 bf16x8 __attribute__((ext_vector_type(8)));
typedef float f32x4 __attribute__((ext_vector_type(4)));

__device__ inline unsigned short f2bf(float f) {
    union { float f; unsigned int u; } a; a.f = f;
    unsigned int u = a.u;
    unsigned int r = (u + 0x7FFFu + ((u >> 16) & 1u)) >> 16;   // RNE
    return (unsigned short)r;
}

// ---- OCP e4m3fn encode (software fallback, RNE) ----
__device__ inline unsigned int f2fp8(float v) {
    unsigned int s = (__float_as_uint(v) >> 31) << 7;
    float av = fabsf(v);
    if (av >= 448.f) return s | 0x7Eu;
    if (av < 0.015625f) {
        unsigned int m = (unsigned int)rintf(av * 512.f);
        return s | m;
    }
    int ex; float fr = frexpf(av, &ex);
    int m = (int)rintf(fr * 16.f - 8.f);
    int e = ex - 1;
    if (m == 8) { m = 0; e += 1; }
    if (e > 8) return s | 0x7Eu;
    return s | (unsigned int)((e + 7) << 3) | (unsigned int)m;
}

#if __has_builtin(__builtin_amdgcn_cvt_f32_fp8)
#define FP8_DEC(d, i) __builtin_amdgcn_cvt_f32_fp8((d), (i))
#else
__device__ inline float fp8_sw_dec(unsigned int d, int i) {
    unsigned int b = (d >> (i * 8)) & 0xFFu;
    unsigned int s = b >> 7, ef = (b >> 3) & 15u, m = b & 7u;
    float v = (ef == 0) ? (float)m * 0.001953125f
                        : __uint_as_float(((ef + 120u) << 23) | (m << 20));
    return s ? -v : v;
}
#define FP8_DEC(d, i) fp8_sw_dec((d), (i))
#endif

// --- prep kernel: 3 block-role ranges (R13-proven).
//     [0,256):        W1||W2 f32 -> bf16 Wc[512][512]
//     [256,1856):     feat f32 -> fp8 table (grid-stride streaming)
//     [1856,3106):    self-row gather: comb[b][0:256] = bf16(feat[nodes[b]]) ---
__global__ __launch_bounds__(256) void prep_kernel(
        const float* __restrict__ W1, const float* __restrict__ W2,
        const float* __restrict__ feat, const int* __restrict__ nodes,
        unsigned short* __restrict__ Wc, unsigned int* __restrict__ tab,
        unsigned short* __restrict__ comb) {
    int blk = blockIdx.x;
    int tid = threadIdx.x;

    if (blk < PB_W) {
        int i = blk * 256 + tid;                     // 65536 float4 chunks
        float4 v = (i < 32768) ? reinterpret_cast<const float4*>(W1)[i]
                               : reinterpret_cast<const float4*>(W2)[i - 32768];
        ushort4 o;
        o.x = f2bf(v.x); o.y = f2bf(v.y); o.z = f2bf(v.z); o.w = f2bf(v.w);
        reinterpret_cast<ushort4*>(Wc)[i] = o;
    } else if (blk < PB_W + PB_CONV) {
        const long long total = (long long)NTOT * D / 4;   // 6.4M dwords
        long long i = (long long)(blk - PB_W) * 256 + tid;
        const long long stride = (long long)PB_CONV * 256;
        for (; i < total; i += stride) {
            float4 v = reinterpret_cast<const float4*>(feat)[i];
#if __has_builtin(__builtin_amdgcn_cvt_pk_fp8_f32)
            int u = __builtin_amdgcn_cvt_pk_fp8_f32(v.x, v.y, 0, 0);
            u = __builtin_amdgcn_cvt_pk_fp8_f32(v.z, v.w, u, 1);
            tab[i] = (unsigned int)u;
#else
            tab[i] = f2fp8(v.x) | (f2fp8(v.y) << 8)
                   | (f2fp8(v.z) << 16) | (f2fp8(v.w) << 24);
#endif
        }
    } else {
        int base = (blk - PB_W - PB_CONV) * 16;
        int lane = tid & 63;
        int wid = tid >> 6;
        const float4* f4 = reinterpret_cast<const float4*>(feat);
        #pragma unroll
        for (int r = 0; r < 4; ++r) {
            int b = base + wid * 4 + r;
            int node = nodes[b];
            float4 s = f4[(size_t)node * 64 + lane];
            ushort4 sv; sv.x = f2bf(s.x); sv.y = f2bf(s.y);
            sv.z = f2bf(s.z); sv.w = f2bf(s.w);
            *reinterpret_cast<ushort4*>(comb + (size_t)b * KDIM + lane * 4) = sv;
        }
    }
}

// --- agg_n: neighbor-only gather from fp8 table -> mean half of comb ---
__global__ __launch_bounds__(256) void agg_n_kernel(
        const int* __restrict__ neigh, const unsigned int* __restrict__ tab,
        unsigned short* __restrict__ comb) {
    int w = threadIdx.x >> 6;
    int lane = threadIdx.x & 63;
    int b = blockIdx.x * 4 + w;                      // grid = 5000
    int nb = b * KN;

    float m0 = 0.f, m1 = 0.f, m2 = 0.f, m3 = 0.f;
    #pragma unroll
    for (int k = 0; k < KN; ++k) {
        int idx = neigh[nb + k];
        unsigned int d = tab[(size_t)idx * 64 + lane];   // 4B/lane = 4 fp8
        m0 += FP8_DEC(d, 0); m1 += FP8_DEC(d, 1);
        m2 += FP8_DEC(d, 2); m3 += FP8_DEC(d, 3);
    }
    const float inv = 1.0f / 16.0f;
    ushort4 mv; mv.x = f2bf(m0 * inv); mv.y = f2bf(m1 * inv);
    mv.z = f2bf(m2 * inv); mv.w = f2bf(m3 * inv);
    *reinterpret_cast<ushort4*>(comb + (size_t)b * KDIM + D + lane * 4) = mv;
}

// --- gemm5: BM=256 x BN=80, BK=64, LDK=72 pad; bijective XCD swizzle pairs
//     m-blocks sharing comb rows on one XCD; non-temporal epilogue stores.
//     (R14-proven best: ~16us) ---
#define G4M 256
#define G4N 80
#define GBK2 64
#define LDK2 72
#define G4BLK 500     // (NB/G4N) * (MDIM/G4M)

__global__ __launch_bounds__(256) void gemm5_kernel(
        const unsigned short* __restrict__ Wc,    // [512][512] bf16
        const unsigned short* __restrict__ Cb,    // [20000][512] bf16
        float* __restrict__ out) {                // [512][20000] f32
    __shared__ __align__(16) unsigned short As[G4M * LDK2];   // 36.9KB
    __shared__ __align__(16) unsigned short Bs[G4N * LDK2];   // 11.5KB

    int b = blockIdx.x;
    const int q = G4BLK / 8, r = G4BLK % 8;       // 62, 4
    int xcd = b & 7, slot = b >> 3;
    int logical = (xcd < r) ? xcd * (q + 1) + slot
                            : r * (q + 1) + (xcd - r) * q + slot;
    int ntile = logical >> 1;                     // 0..249
    int mtile = logical & 1;                      // 0..1

    int tid = threadIdx.x;
    int lane = tid & 63;
    int wid = tid >> 6;                 // 0..3 -> m-slice of 64
    int mBase = mtile * G4M;
    int nBase = ntile * G4N;            // exact fit: 250*80 = 20000

    f32x4 acc[4][5] = {};

    int srow8 = tid >> 3;               // 0..31
    int scol8 = (tid & 7) * 8;          // 0..56 elems within 64
    int rl = lane & 15;
    int kq = (lane >> 4) * 8;

    for (int k0 = 0; k0 < KDIM; k0 += GBK2) {
        // stage A: 256 rows x 64 elems = 2048 16B-chunks; 8 per thread
        #pragma unroll
        for (int h = 0; h < 8; ++h) {
            int rr = srow8 + h * 32;
            uint4 va = *reinterpret_cast<const uint4*>(
                Wc + (size_t)(mBase + rr) * KDIM + k0 + scol8);
            *reinterpret_cast<uint4*>(&As[rr * LDK2 + scol8]) = va;
        }
        // stage B: 80 rows x 8 chunks = 640 chunks; 256+256+128
        {
            int c = tid;                            // 0..255
            int rr = c >> 3, ch = (c & 7) * 8;
            uint4 vb = *reinterpret_cast<const uint4*>(
                Cb + (size_t)(nBase + rr) * KDIM + k0 + ch);
            *reinterpret_cast<uint4*>(&Bs[rr * LDK2 + ch]) = vb;
            int c1 = tid + 256;
            int r1 = c1 >> 3, ch1 = (c1 & 7) * 8;
            uint4 v1 = *reinterpret_cast<const uint4*>(
                Cb + (size_t)(nBase + r1) * KDIM + k0 + ch1);
            *reinterpret_cast<uint4*>(&Bs[r1 * LDK2 + ch1]) = v1;
            if (tid < 128) {
                int c2 = tid + 512;
                int r2 = c2 >> 3, ch2 = (c2 & 7) * 8;
                uint4 v2 = *reinterpret_cast<const uint4*>(
                    Cb + (size_t)(nBase + r2) * KDIM + k0 + ch2);
                *reinterpret_cast<uint4*>(&Bs[r2 * LDK2 + ch2]) = v2;
            }
        }
        __syncthreads();

        #pragma unroll
        for (int kk = 0; kk < GBK2; kk += 32) {
            bf16x8 af[4], bfr[5];
            #pragma unroll
            for (int i = 0; i < 4; ++i)
                af[i] = *reinterpret_cast<const bf16x8*>(
                    &As[(wid * 64 + i * 16 + rl) * LDK2 + kk + kq]);
            #pragma unroll
            for (int j = 0; j < 5; ++j)
                bfr[j] = *reinterpret_cast<const bf16x8*>(
                    &Bs[(j * 16 + rl) * LDK2 + kk + kq]);
            #pragma unroll
            for (int i = 0; i < 4; ++i)
                #pragma unroll
                for (int j = 0; j < 5; ++j)
                    acc[i][j] = __builtin_amdgcn_mfma_f32_16x16x32_bf16(
                        af[i], bfr[j], acc[i][j], 0, 0, 0);
        }
        __syncthreads();
    }

    // epilogue: C/D layout col=lane&15, row=(lane>>4)*4+reg (verified);
    // non-temporal stores to avoid evicting comb/Wc from L2
    int col = lane & 15;
    int rq = (lane >> 4) * 4;
    #pragma unroll
    for (int i = 0; i < 4; ++i) {
        int mRow = mBase + wid * 64 + i * 16 + rq;
        #pragma unroll
        for (int j = 0; j < 5; ++j) {
            int n = nBase + j * 16 + col;             // always < NB
            #pragma unroll
            for (int rr = 0; rr < 4; ++rr) {
                float x = acc[i][j][rr];
                x = x > 0.f ? x : 0.f;
                __builtin_nontemporal_store(x, &out[(size_t)(mRow + rr) * NB + n]);
            }
        }
    }
}

extern "C" void kernel_launch(void* const* d_in, const int* in_sizes, int n_in,
                              void* d_out, int out_size, void* d_ws, size_t ws_size,
                              hipStream_t stream) {
    const int*   nodes = (const int*)d_in[0];
    const int*   neigh = (const int*)d_in[1];
    const float* feat  = (const float*)d_in[2];
    const float* W1    = (const float*)d_in[3];
    const float* W2    = (const float*)d_in[4];
    float* out = (float*)d_out;

    // ws layout: Wc (512KB) | fp8 table (25.6MB) | comb (20.48MB)
    const size_t WC_BYTES  = (size_t)MDIM * KDIM * 2;
    const size_t TAB_BYTES = (size_t)NTOT * D;
    unsigned short* Wc   = (unsigned short*)d_ws;
    unsigned int*   tab  = (unsigned int*)((char*)d_ws + WC_BYTES);
    unsigned short* comb = (unsigned short*)((char*)d_ws + WC_BYTES + TAB_BYTES);

    prep_kernel<<<PB_TOT, 256, 0, stream>>>(W1, W2, feat, nodes, Wc, tab, comb);
    agg_n_kernel<<<NB / 4, 256, 0, stream>>>(neigh, tab, comb);
    gemm5_kernel<<<G4BLK, 256, 0, stream>>>(Wc, comb, out);
}